// Round 3
// baseline (41.369 us; speedup 1.0000x reference)
//
#include <hip/hip_runtime.h>

#define BATCH 32
#define DD 64
#define NN 8
#define SS 128
#define EPS_ 1e-6f
#define GROUPS 16
#define GSTEP 8
#define NTHREADS 1024

// deg-6 Taylor coefficients for exp(c*X) = sum c^k/k! X^k
#define E1_2 0.5f
#define E1_3 0.16666666666667f
#define E1_4 0.04166666666667f
#define E1_5 0.00833333333333f
#define E1_6 0.00138888888889f
#define E8_1 8.f
#define E8_2 32.f
#define E8_3 85.33333333f
#define E8_4 170.66666667f
#define E8_5 273.06666667f
#define E8_6 364.08888889f
#define E16_1 16.f
#define E16_2 128.f
#define E16_3 682.66666667f
#define E16_4 2730.66666667f
#define E16_5 8738.13333333f
#define E16_6 23301.68888889f

// rows i4..i4+3 of A*B accumulated into acc[4]. A rows broadcast b128, B rows lane-coalesced b32.
__device__ __forceinline__ void mm_rows(const float* __restrict__ A,
                                        const float* __restrict__ Bm,
                                        float acc[4], int i4, int j)
{
#pragma unroll 4
    for (int kc = 0; kc < DD; kc += 4) {
        float4 a0 = *(const float4*)&A[(i4 + 0) * DD + kc];
        float4 a1 = *(const float4*)&A[(i4 + 1) * DD + kc];
        float4 a2 = *(const float4*)&A[(i4 + 2) * DD + kc];
        float4 a3 = *(const float4*)&A[(i4 + 3) * DD + kc];
        float bv0 = Bm[(kc + 0) * DD + j];
        float bv1 = Bm[(kc + 1) * DD + j];
        float bv2 = Bm[(kc + 2) * DD + j];
        float bv3 = Bm[(kc + 3) * DD + j];
        acc[0] = fmaf(a0.x, bv0, fmaf(a0.y, bv1, fmaf(a0.z, bv2, fmaf(a0.w, bv3, acc[0]))));
        acc[1] = fmaf(a1.x, bv0, fmaf(a1.y, bv1, fmaf(a1.z, bv2, fmaf(a1.w, bv3, acc[1]))));
        acc[2] = fmaf(a2.x, bv0, fmaf(a2.y, bv1, fmaf(a2.z, bv2, fmaf(a2.w, bv3, acc[2]))));
        acc[3] = fmaf(a3.x, bv0, fmaf(a3.y, bv1, fmaf(a3.z, bv2, fmaf(a3.w, bv3, acc[3]))));
    }
}

// ===================== Kernel A: build M, M8, M16 per batch -> ws =====================
__launch_bounds__(NTHREADS)
__global__ void htg_build(const float* __restrict__ time_steps,
                          const float* __restrict__ k_coeffs,
                          const float* __restrict__ r_coeffs,
                          const float* __restrict__ alpha_p,
                          const float* __restrict__ beta_p,
                          const float* __restrict__ K_bases,
                          const float* __restrict__ R_bases,
                          float* __restrict__ ws)
{
    __shared__ float b0[DD * DD];   // Ksum(swz) -> X2
    __shared__ float b1[DD * DD];   // Rsum -> X3
    __shared__ float b2[DD * DD];   // X

    const int tid  = threadIdx.x;
    const int b    = blockIdx.x;
    const int wave = tid >> 6;
    const int lane = tid & 63;
    const int i4   = wave * 4;
    const int j    = lane;

    const float alpha = alpha_p[b];
    const float beta  = beta_p[b];
    const float dt    = time_steps[0];
    float kc[NN], rc[NN];
#pragma unroll
    for (int n = 0; n < NN; ++n) {
        kc[n] = k_coeffs[b * NN + n];
        rc[n] = r_coeffs[b * NN + n];
    }

    // Phase A: Ksum (XOR-swizzled for transpose reads) -> b0, Rsum -> b1
    {
        const int i  = tid >> 4;
        const int j0 = (tid & 15) * 4;
        const int e4 = i * DD + j0;
        float4 ks = make_float4(0.f, 0.f, 0.f, 0.f);
        float4 rs = make_float4(0.f, 0.f, 0.f, 0.f);
#pragma unroll
        for (int n = 0; n < NN; ++n) {
            float4 kb = *(const float4*)&K_bases[n * DD * DD + e4];
            float4 rb = *(const float4*)&R_bases[n * DD * DD + e4];
            ks.x = fmaf(kc[n], kb.x, ks.x); ks.y = fmaf(kc[n], kb.y, ks.y);
            ks.z = fmaf(kc[n], kb.z, ks.z); ks.w = fmaf(kc[n], kb.w, ks.w);
            rs.x = fmaf(rc[n], rb.x, rs.x); rs.y = fmaf(rc[n], rb.y, rs.y);
            rs.z = fmaf(rc[n], rb.z, rs.z); rs.w = fmaf(rc[n], rb.w, rs.w);
        }
        const int c = i & 31;
        b0[i * DD + ((j0 + 0) ^ c)] = ks.x;
        b0[i * DD + ((j0 + 1) ^ c)] = ks.y;
        b0[i * DD + ((j0 + 2) ^ c)] = ks.z;
        b0[i * DD + ((j0 + 3) ^ c)] = ks.w;
        *(float4*)&b1[e4] = rs;
    }
    __syncthreads();

    // MM1: X = dt*(alpha*(K-K^T) - beta*(R^T R)) + eps*I -> b2
    {
        float acc[4] = {0.f, 0.f, 0.f, 0.f};
#pragma unroll 8
        for (int k = 0; k < DD; ++k) {
            float rk = b1[k * DD + j];
#pragma unroll
            for (int r = 0; r < 4; ++r) {
                float ar = __uint_as_float(__builtin_amdgcn_readlane(__float_as_uint(rk), i4 + r));
                acc[r] = fmaf(ar, rk, acc[r]);
            }
        }
#pragma unroll
        for (int r = 0; r < 4; ++r) {
            const int i = i4 + r;
            float kij = b0[i * DD + (j ^ (i & 31))];
            float kji = b0[j * DD + (i ^ (j & 31))];
            float x = dt * (alpha * (kij - kji) - beta * acc[r]);
            if (i == j) x += EPS_;
            acc[r] = x;
        }
        __syncthreads();   // all swizzled-K reads done before b0 reuse; Rsum reads done
#pragma unroll
        for (int r = 0; r < 4; ++r) b2[(i4 + r) * DD + j] = acc[r];
    }
    __syncthreads();

    // MM2: X2 = X*X -> b0
    {
        float acc[4] = {0.f, 0.f, 0.f, 0.f};
        mm_rows(b2, b2, acc, i4, j);
#pragma unroll
        for (int r = 0; r < 4; ++r) b0[(i4 + r) * DD + j] = acc[r];
    }
    __syncthreads();

    // MM3: X3 = X2*X -> b1
    {
        float acc[4] = {0.f, 0.f, 0.f, 0.f};
        mm_rows(b0, b2, acc, i4, j);
#pragma unroll
        for (int r = 0; r < 4; ++r) b1[(i4 + r) * DD + j] = acc[r];
    }
    __syncthreads();

    // In-register dots: x4 = X2*X2, x5 = X2*X3, x6 = X3*X3 (powers of X commute)
    float x1v[4], x2v[4], x3v[4];
    float x4v[4] = {0.f, 0.f, 0.f, 0.f};
    float x5v[4] = {0.f, 0.f, 0.f, 0.f};
    float x6v[4] = {0.f, 0.f, 0.f, 0.f};
#pragma unroll
    for (int r = 0; r < 4; ++r) {
        x1v[r] = b2[(i4 + r) * DD + j];
        x2v[r] = b0[(i4 + r) * DD + j];
        x3v[r] = b1[(i4 + r) * DD + j];
    }
#pragma unroll 4
    for (int kc = 0; kc < DD; kc += 4) {
        float4 a2r[4], a3r[4];
#pragma unroll
        for (int r = 0; r < 4; ++r) {
            a2r[r] = *(const float4*)&b0[(i4 + r) * DD + kc];
            a3r[r] = *(const float4*)&b1[(i4 + r) * DD + kc];
        }
        float c20 = b0[(kc + 0) * DD + j], c21 = b0[(kc + 1) * DD + j];
        float c22 = b0[(kc + 2) * DD + j], c23 = b0[(kc + 3) * DD + j];
        float c30 = b1[(kc + 0) * DD + j], c31 = b1[(kc + 1) * DD + j];
        float c32 = b1[(kc + 2) * DD + j], c33 = b1[(kc + 3) * DD + j];
#pragma unroll
        for (int r = 0; r < 4; ++r) {
            x4v[r] = fmaf(a2r[r].x, c20, fmaf(a2r[r].y, c21, fmaf(a2r[r].z, c22, fmaf(a2r[r].w, c23, x4v[r]))));
            x5v[r] = fmaf(a2r[r].x, c30, fmaf(a2r[r].y, c31, fmaf(a2r[r].z, c32, fmaf(a2r[r].w, c33, x5v[r]))));
            x6v[r] = fmaf(a3r[r].x, c30, fmaf(a3r[r].y, c31, fmaf(a3r[r].z, c32, fmaf(a3r[r].w, c33, x6v[r]))));
        }
    }

    // Elementwise deg-6 combos -> global ws: [b][0]=M, [b][1]=M8, [b][2]=M16
    float* wsb = ws + (size_t)b * 3 * DD * DD;
#pragma unroll
    for (int r = 0; r < 4; ++r) {
        const int i = i4 + r;
        const float d  = (i == j) ? 1.f : 0.f;
        const float x  = x1v[r], x2 = x2v[r], x3 = x3v[r];
        const float x4 = x4v[r], x5 = x5v[r], x6 = x6v[r];
        float m1 = d + x + E1_2 * x2 + E1_3 * x3 + E1_4 * x4 + E1_5 * x5 + E1_6 * x6;
        float m8 = d + E8_1 * x + E8_2 * x2 + E8_3 * x3 + E8_4 * x4 + E8_5 * x5 + E8_6 * x6;
        float mg = d + E16_1 * x + E16_2 * x2 + E16_3 * x3 + E16_4 * x4 + E16_5 * x5 + E16_6 * x6;
        wsb[0 * DD * DD + i * DD + j] = m1;
        wsb[1 * DD * DD + i * DD + j] = m8;
        wsb[2 * DD * DD + i * DD + j] = mg;
    }
}

// block-wide matvec: row mi, k-chunk 4*mh; contiguous per wave -> conflict-free
__device__ __forceinline__ float mv_step(const float* __restrict__ Mat,
                                         const float* __restrict__ vsrc,
                                         int mi, int mh)
{
    float4 m = *(const float4*)&Mat[mi * DD + 4 * mh];
    float4 v = *(const float4*)&vsrc[4 * mh];
    float p = fmaf(m.x, v.x, fmaf(m.y, v.y, fmaf(m.z, v.z, m.w * v.w)));
    p += __shfl_xor(p, 1, 16);
    p += __shfl_xor(p, 2, 16);
    p += __shfl_xor(p, 4, 16);
    p += __shfl_xor(p, 8, 16);
    return p;
}

// ===================== Kernel B: per (batch, group) propagate 8 steps =====================
__launch_bounds__(NTHREADS)
__global__ void htg_prop(const float* __restrict__ z0,
                         const float* __restrict__ ws,
                         float* __restrict__ out,
                         int interleaved)
{
    __shared__ float sM[DD * DD];
    __shared__ float sP16[DD * DD];
    __shared__ float vb[2][DD];

    const int tid = threadIdx.x;
    const int bid = blockIdx.x;
    const int b   = bid >> 4;
    const int g   = bid & 15;
    const int mi  = tid >> 4;
    const int mh  = tid & 15;

    const float* wsb = ws + (size_t)b * 3 * DD * DD;

    // stage M and M16 (1 float4 per thread each)
    *(float4*)&sM[tid * 4]   = *(const float4*)&wsb[0 * DD * DD + tid * 4];
    *(float4*)&sP16[tid * 4] = *(const float4*)&wsb[2 * DD * DD + tid * 4];
    if (tid < DD) vb[0][tid] = z0[b * DD + tid];
    __syncthreads();

    int pp = 0;
    // vbase = M8^(g&1) * M16^(g>>1) * z0   (powers of M commute)
    if (g & 1) {
        float val = mv_step(&wsb[1 * DD * DD], vb[pp], mi, mh);  // M8 from L2-hot global
        if (mh == 0) vb[pp ^ 1][mi] = val;
        __syncthreads();
        pp ^= 1;
    }
    const int n16 = g >> 1;
    for (int a = 0; a < n16; ++a) {
        float val = mv_step(sP16, vb[pp], mi, mh);
        if (mh == 0) vb[pp ^ 1][mi] = val;
        __syncthreads();
        pp ^= 1;
    }
    // chain: 8 steps with M; emit s = 8g + t
    for (int t = 0; t < GSTEP; ++t) {
        float val = mv_step(sM, vb[pp], mi, mh);
        if (mh == 0) {
            vb[pp ^ 1][mi] = val;
            const int s = g * GSTEP + t;
            const size_t oi = ((size_t)(b * SS + s)) * DD + mi;
            if (interleaved) ((float2*)out)[oi] = make_float2(val, 0.f);
            else             out[oi] = val;
        }
        __syncthreads();
        pp ^= 1;
    }
}

extern "C" void kernel_launch(void* const* d_in, const int* in_sizes, int n_in,
                              void* d_out, int out_size, void* d_ws, size_t ws_size,
                              hipStream_t stream) {
    const float* z0         = (const float*)d_in[0];
    const float* time_steps = (const float*)d_in[1];
    const float* k_coeffs   = (const float*)d_in[2];
    const float* r_coeffs   = (const float*)d_in[3];
    const float* alpha      = (const float*)d_in[4];
    const float* beta       = (const float*)d_in[5];
    const float* K_bases    = (const float*)d_in[6];
    const float* R_bases    = (const float*)d_in[7];
    float* out = (float*)d_out;
    float* wsf = (float*)d_ws;

    const int n_z = BATCH * SS * DD;
    const int interleaved = (out_size >= 2 * n_z) ? 1 : 0;

    htg_build<<<dim3(BATCH), dim3(NTHREADS), 0, stream>>>(
        time_steps, k_coeffs, r_coeffs, alpha, beta, K_bases, R_bases, wsf);
    htg_prop<<<dim3(BATCH * GROUPS), dim3(NTHREADS), 0, stream>>>(
        z0, wsf, out, interleaved);
}

// Round 5
// 33.597 us; speedup vs baseline: 1.2313x; 1.2313x over previous
//
#include <hip/hip_runtime.h>

#define BATCH 32
#define DD 64
#define NN 8
#define SS 128
#define EPS_ 1e-6f
#define GROUPS 8
#define GSTEP 16
#define NTHREADS 1024

// deg-6 Taylor coefficients for exp(c*X) = sum c^k/k! X^k
#define E1_2 0.5f
#define E1_3 0.16666666666667f
#define E1_4 0.04166666666667f
#define E1_5 0.00833333333333f
#define E1_6 0.00138888888889f
// c = 16
#define E16_1 16.f
#define E16_2 128.f
#define E16_3 682.66666667f
#define E16_4 2730.66666667f
#define E16_5 8738.13333333f
#define E16_6 23301.68888889f
// c = 32
#define E32_1 32.f
#define E32_2 512.f
#define E32_3 5461.33333333f
#define E32_4 43690.66666667f
#define E32_5 279620.26666667f
#define E32_6 1491308.08888889f

// rows i4..i4+3 of A*B accumulated into acc[4]. A rows broadcast b128, B cols lane-coalesced b32.
__device__ __forceinline__ void mm_rows(const float* __restrict__ A,
                                        const float* __restrict__ Bm,
                                        float acc[4], int i4, int j)
{
#pragma unroll 4
    for (int kc = 0; kc < DD; kc += 4) {
        float4 a0 = *(const float4*)&A[(i4 + 0) * DD + kc];
        float4 a1 = *(const float4*)&A[(i4 + 1) * DD + kc];
        float4 a2 = *(const float4*)&A[(i4 + 2) * DD + kc];
        float4 a3 = *(const float4*)&A[(i4 + 3) * DD + kc];
        float bv0 = Bm[(kc + 0) * DD + j];
        float bv1 = Bm[(kc + 1) * DD + j];
        float bv2 = Bm[(kc + 2) * DD + j];
        float bv3 = Bm[(kc + 3) * DD + j];
        acc[0] = fmaf(a0.x, bv0, fmaf(a0.y, bv1, fmaf(a0.z, bv2, fmaf(a0.w, bv3, acc[0]))));
        acc[1] = fmaf(a1.x, bv0, fmaf(a1.y, bv1, fmaf(a1.z, bv2, fmaf(a1.w, bv3, acc[1]))));
        acc[2] = fmaf(a2.x, bv0, fmaf(a2.y, bv1, fmaf(a2.z, bv2, fmaf(a2.w, bv3, acc[2]))));
        acc[3] = fmaf(a3.x, bv0, fmaf(a3.y, bv1, fmaf(a3.z, bv2, fmaf(a3.w, bv3, acc[3]))));
    }
}

// fused: acc0 += A*B0, acc1 += A*B1 (shared A-row reads)
__device__ __forceinline__ void mm_rows2(const float* __restrict__ A,
                                         const float* __restrict__ B0m,
                                         const float* __restrict__ B1m,
                                         float acc0[4], float acc1[4], int i4, int j)
{
#pragma unroll 4
    for (int kc = 0; kc < DD; kc += 4) {
        float4 a0 = *(const float4*)&A[(i4 + 0) * DD + kc];
        float4 a1 = *(const float4*)&A[(i4 + 1) * DD + kc];
        float4 a2 = *(const float4*)&A[(i4 + 2) * DD + kc];
        float4 a3 = *(const float4*)&A[(i4 + 3) * DD + kc];
        float p0 = B0m[(kc + 0) * DD + j], q0 = B1m[(kc + 0) * DD + j];
        float p1 = B0m[(kc + 1) * DD + j], q1 = B1m[(kc + 1) * DD + j];
        float p2 = B0m[(kc + 2) * DD + j], q2 = B1m[(kc + 2) * DD + j];
        float p3 = B0m[(kc + 3) * DD + j], q3 = B1m[(kc + 3) * DD + j];
        acc0[0] = fmaf(a0.x, p0, fmaf(a0.y, p1, fmaf(a0.z, p2, fmaf(a0.w, p3, acc0[0]))));
        acc0[1] = fmaf(a1.x, p0, fmaf(a1.y, p1, fmaf(a1.z, p2, fmaf(a1.w, p3, acc0[1]))));
        acc0[2] = fmaf(a2.x, p0, fmaf(a2.y, p1, fmaf(a2.z, p2, fmaf(a2.w, p3, acc0[2]))));
        acc0[3] = fmaf(a3.x, p0, fmaf(a3.y, p1, fmaf(a3.z, p2, fmaf(a3.w, p3, acc0[3]))));
        acc1[0] = fmaf(a0.x, q0, fmaf(a0.y, q1, fmaf(a0.z, q2, fmaf(a0.w, q3, acc1[0]))));
        acc1[1] = fmaf(a1.x, q0, fmaf(a1.y, q1, fmaf(a1.z, q2, fmaf(a1.w, q3, acc1[1]))));
        acc1[2] = fmaf(a2.x, q0, fmaf(a2.y, q1, fmaf(a2.z, q2, fmaf(a2.w, q3, acc1[2]))));
        acc1[3] = fmaf(a3.x, q0, fmaf(a3.y, q1, fmaf(a3.z, q2, fmaf(a3.w, q3, acc1[3]))));
    }
}

// block-wide matvec: row mi (tid>>4), k-chunk mh (tid&15); butterfly over 16 lanes
__device__ __forceinline__ float mv_step(const float* __restrict__ Mat,
                                         const float* __restrict__ vsrc,
                                         int mi, int mh)
{
    float4 m = *(const float4*)&Mat[mi * DD + 4 * mh];
    float4 v = *(const float4*)&vsrc[4 * mh];
    float p = fmaf(m.x, v.x, fmaf(m.y, v.y, fmaf(m.z, v.z, m.w * v.w)));
    p += __shfl_xor(p, 1, 16);
    p += __shfl_xor(p, 2, 16);
    p += __shfl_xor(p, 4, 16);
    p += __shfl_xor(p, 8, 16);
    return p;
}

__launch_bounds__(NTHREADS)
__global__ void htg_kernel(const float* __restrict__ z0,
                           const float* __restrict__ time_steps,
                           const float* __restrict__ k_coeffs,
                           const float* __restrict__ r_coeffs,
                           const float* __restrict__ alpha_p,
                           const float* __restrict__ beta_p,
                           const float* __restrict__ K_bases,
                           const float* __restrict__ R_bases,
                           float* __restrict__ out,
                           int interleaved)
{
    __shared__ float b0[DD * DD];   // X            -> M
    __shared__ float b1[DD * DD];   // Rsum -> X2   -> M32
    __shared__ float b2[DD * DD];   // Kswz -> X4   -> M16
    __shared__ float vb[2][DD];

    const int tid  = threadIdx.x;
    const int bg   = blockIdx.x;
    const int b    = bg >> 3;       // batch
    const int g    = bg & 7;        // step-group: s in [16g, 16g+16)
    const int wave = tid >> 6;
    const int lane = tid & 63;
    const int i4   = wave * 4;
    const int j    = lane;
    const int mi   = tid >> 4;
    const int mh   = tid & 15;

    const float alpha = alpha_p[b];
    const float beta  = beta_p[b];
    const float dt    = time_steps[0];   // uniform grid
    float kc[NN], rc[NN];
#pragma unroll
    for (int n = 0; n < NN; ++n) {
        kc[n] = k_coeffs[b * NN + n];
        rc[n] = r_coeffs[b * NN + n];
    }
    if (tid < DD) vb[0][tid] = z0[b * DD + tid];

    // ---- Phase A: Ksum (XOR-swizzled) -> b2, Rsum -> b1 ----
    {
        const int i  = tid >> 4;
        const int j0 = (tid & 15) * 4;
        const int e4 = i * DD + j0;
        float4 ks = make_float4(0.f, 0.f, 0.f, 0.f);
        float4 rs = make_float4(0.f, 0.f, 0.f, 0.f);
#pragma unroll
        for (int n = 0; n < NN; ++n) {
            float4 kb = *(const float4*)&K_bases[n * DD * DD + e4];
            float4 rb = *(const float4*)&R_bases[n * DD * DD + e4];
            ks.x = fmaf(kc[n], kb.x, ks.x); ks.y = fmaf(kc[n], kb.y, ks.y);
            ks.z = fmaf(kc[n], kb.z, ks.z); ks.w = fmaf(kc[n], kb.w, ks.w);
            rs.x = fmaf(rc[n], rb.x, rs.x); rs.y = fmaf(rc[n], rb.y, rs.y);
            rs.z = fmaf(rc[n], rb.z, rs.z); rs.w = fmaf(rc[n], rb.w, rs.w);
        }
        const int c = i & 31;   // swizzle: addr(i,j) = i*64 + (j^c); column reads conflict-free
        b2[i * DD + ((j0 + 0) ^ c)] = ks.x;
        b2[i * DD + ((j0 + 1) ^ c)] = ks.y;
        b2[i * DD + ((j0 + 2) ^ c)] = ks.z;
        b2[i * DD + ((j0 + 3) ^ c)] = ks.w;
        *(float4*)&b1[e4] = rs;
    }
    __syncthreads();

    // ---- MM1: X = dt*(alpha*(K-K^T) - beta*(R^T R)) + eps*I -> b0 (fresh buffer) ----
    {
        float acc[4] = {0.f, 0.f, 0.f, 0.f};
#pragma unroll 8
        for (int k = 0; k < DD; ++k) {
            float rk = b1[k * DD + j];           // coalesced row of Rsum
#pragma unroll
            for (int r = 0; r < 4; ++r) {        // (R^T R)[i][j] = sum_k R[k][i]*R[k][j]
                float ar = __uint_as_float(__builtin_amdgcn_readlane(__float_as_uint(rk), i4 + r));
                acc[r] = fmaf(ar, rk, acc[r]);
            }
        }
#pragma unroll
        for (int r = 0; r < 4; ++r) {
            const int i = i4 + r;
            float kij = b2[i * DD + (j ^ (i & 31))];
            float kji = b2[j * DD + (i ^ (j & 31))];
            float x = dt * (alpha * (kij - kji) - beta * acc[r]);
            if (i == j) x += EPS_;
            b0[i * DD + j] = x;
        }
    }
    __syncthreads();

    // ---- MM2: X2 = X*X -> b1 (Rsum dead) ----
    {
        float acc[4] = {0.f, 0.f, 0.f, 0.f};
        mm_rows(b0, b0, acc, i4, j);   // reads b0 only; write target b1 already quiesced
#pragma unroll
        for (int r = 0; r < 4; ++r) b1[(i4 + r) * DD + j] = acc[r];
    }
    __syncthreads();

    // ---- L2 fused: X3 = X2*X (regs), X4 = X2*X2 -> b2 (Kswz dead) ----
    float x3v[4] = {0.f, 0.f, 0.f, 0.f};
    float x4v[4] = {0.f, 0.f, 0.f, 0.f};
    mm_rows2(b1, b0, b1, x3v, x4v, i4, j);
#pragma unroll
    for (int r = 0; r < 4; ++r) b2[(i4 + r) * DD + j] = x4v[r];
    __syncthreads();

    // ---- L3 fused: X5 = X4*X (regs), X6 = X4*X2 (regs); preload x1,x2 tiles ----
    float x5v[4] = {0.f, 0.f, 0.f, 0.f};
    float x6v[4] = {0.f, 0.f, 0.f, 0.f};
    mm_rows2(b2, b0, b1, x5v, x6v, i4, j);
    float x1v[4], x2v[4];
#pragma unroll
    for (int r = 0; r < 4; ++r) {
        x1v[r] = b0[(i4 + r) * DD + j];
        x2v[r] = b1[(i4 + r) * DD + j];
    }
    __syncthreads();   // all reads of b0/b1/b2 done before overwriting with M/M32/M16

    // ---- Elementwise deg-6 combos: M -> b0, M32 -> b1, M16 -> b2 ----
#pragma unroll
    for (int r = 0; r < 4; ++r) {
        const int i = i4 + r;
        const float d  = (i == j) ? 1.f : 0.f;
        const float x  = x1v[r], x2 = x2v[r], x3 = x3v[r];
        const float x4 = x4v[r], x5 = x5v[r], x6 = x6v[r];
        b0[i * DD + j] = d + x + E1_2 * x2 + E1_3 * x3 + E1_4 * x4 + E1_5 * x5 + E1_6 * x6;
        b1[i * DD + j] = d + E32_1 * x + E32_2 * x2 + E32_3 * x3 + E32_4 * x4 + E32_5 * x5 + E32_6 * x6;
        b2[i * DD + j] = d + E16_1 * x + E16_2 * x2 + E16_3 * x3 + E16_4 * x4 + E16_5 * x5 + E16_6 * x6;
    }
    __syncthreads();

    // ---- base: v = M32^(g>>1) * M16^(g&1) * z0 = M^(16g) * z0  (<= 4 matvecs) ----
    int pp = 0;
    const int n32 = g >> 1;
    for (int a = 0; a < n32; ++a) {
        float val = mv_step(b1, vb[pp], mi, mh);
        if (mh == 0) vb[pp ^ 1][mi] = val;
        __syncthreads();
        pp ^= 1;
    }
    if (g & 1) {
        float val = mv_step(b2, vb[pp], mi, mh);
        if (mh == 0) vb[pp ^ 1][mi] = val;
        __syncthreads();
        pp ^= 1;
    }

    // ---- chain: 16 steps with M; emit s = 16g + t ----
    for (int t = 0; t < GSTEP; ++t) {
        float val = mv_step(b0, vb[pp], mi, mh);
        if (mh == 0) {
            vb[pp ^ 1][mi] = val;
            const int s = g * GSTEP + t;
            const size_t oi = ((size_t)(b * SS + s)) * DD + mi;
            if (interleaved) ((float2*)out)[oi] = make_float2(val, 0.f);
            else             out[oi] = val;
        }
        __syncthreads();
        pp ^= 1;
    }
}

extern "C" void kernel_launch(void* const* d_in, const int* in_sizes, int n_in,
                              void* d_out, int out_size, void* d_ws, size_t ws_size,
                              hipStream_t stream) {
    const float* z0         = (const float*)d_in[0];
    const float* time_steps = (const float*)d_in[1];
    const float* k_coeffs   = (const float*)d_in[2];
    const float* r_coeffs   = (const float*)d_in[3];
    const float* alpha      = (const float*)d_in[4];
    const float* beta       = (const float*)d_in[5];
    const float* K_bases    = (const float*)d_in[6];
    const float* R_bases    = (const float*)d_in[7];
    float* out = (float*)d_out;

    const int n_z = BATCH * SS * DD;
    const int interleaved = (out_size >= 2 * n_z) ? 1 : 0;

    htg_kernel<<<dim3(BATCH * GROUPS), dim3(NTHREADS), 0, stream>>>(
        z0, time_steps, k_coeffs, r_coeffs, alpha, beta, K_bases, R_bases,
        out, interleaved);
}

// Round 6
// 22.551 us; speedup vs baseline: 1.8345x; 1.4898x over previous
//
#include <hip/hip_runtime.h>

#define BATCH 32
#define DD 64
#define NN 8
#define SS 128
#define EPS_ 1e-6f
#define GROUPS 8
#define GSTEP 16
#define NTHREADS 1024

// deg-6 Taylor coefficients for exp(c*X) = sum c^k/k! X^k
#define E1_2 0.5f
#define E1_3 0.16666666666667f
#define E1_4 0.04166666666667f
#define E1_5 0.00833333333333f
#define E1_6 0.00138888888889f
#define E16_1 16.f
#define E16_2 128.f
#define E16_3 682.66666667f
#define E16_4 2730.66666667f
#define E16_5 8738.13333333f
#define E16_6 23301.68888889f
#define E32_1 32.f
#define E32_2 512.f
#define E32_3 5461.33333333f
#define E32_4 43690.66666667f
#define E32_5 279620.26666667f
#define E32_6 1491308.08888889f

typedef __attribute__((ext_vector_type(8))) short bf16x8;
typedef __attribute__((ext_vector_type(4))) float f32x4;

__device__ __forceinline__ unsigned short f2bf(float f) {
    unsigned u = __float_as_uint(f);
    unsigned r = u + 0x7FFFu + ((u >> 16) & 1u);   // round-to-nearest-even
    return (unsigned short)(r >> 16);
}
__device__ __forceinline__ float bf2f(unsigned short h) {
    return __uint_as_float(((unsigned)h) << 16);
}
// swizzled element index in a [64][64] bf16 matrix: keeps 8-elem k-blocks contiguous,
// XORs block index with (row&7) so column reads spread across banks
__device__ __forceinline__ int SWZ(int r, int c) {
    return r * 64 + (((c & ~7) ^ ((r & 7) << 3)) | (c & 7));
}
// A-fragment: 8 contiguous bf16 of row `row`, k-block k0 (multiple of 8)
__device__ __forceinline__ bf16x8 ldrow(const short* m, int row, int k0) {
    return *(const bf16x8*)&m[row * 64 + (k0 ^ ((row & 7) << 3))];
}
// B-fragment: 8 bf16 of column `col`, rows k0..k0+7
__device__ __forceinline__ bf16x8 ldcol(const short* m, int k0, int col) {
    bf16x8 v;
#pragma unroll
    for (int i = 0; i < 8; ++i) v[i] = m[SWZ(k0 + i, col)];
    return v;
}

#define MFMA(a, b, c) __builtin_amdgcn_mfma_f32_16x16x32_bf16((a), (b), (c), 0, 0, 0)

// block-wide matvec: row mi (tid>>4), k-chunk mh (tid&15); butterfly over 16 lanes
__device__ __forceinline__ float mv_step(const float* __restrict__ Mat,
                                         const float* __restrict__ vsrc,
                                         int mi, int mh)
{
    float4 m = *(const float4*)&Mat[mi * DD + 4 * mh];
    float4 v = *(const float4*)&vsrc[4 * mh];
    float p = fmaf(m.x, v.x, fmaf(m.y, v.y, fmaf(m.z, v.z, m.w * v.w)));
    p += __shfl_xor(p, 1, 16);
    p += __shfl_xor(p, 2, 16);
    p += __shfl_xor(p, 4, 16);
    p += __shfl_xor(p, 8, 16);
    return p;
}

__launch_bounds__(NTHREADS)
__global__ void htg_kernel(const float* __restrict__ z0,
                           const float* __restrict__ time_steps,
                           const float* __restrict__ k_coeffs,
                           const float* __restrict__ r_coeffs,
                           const float* __restrict__ alpha_p,
                           const float* __restrict__ beta_p,
                           const float* __restrict__ K_bases,
                           const float* __restrict__ R_bases,
                           float* __restrict__ out,
                           int interleaved)
{
    __shared__ float b0[DD * DD];   // rh/rl (bf16 split R) -> X fp32 -> M
    __shared__ float b1[DD * DD];   // xh/xl (bf16 split X) -> M32
    __shared__ float b2[DD * DD];   // Ksum fp32 (elem-XOR) -> x2h/x2l -> M16
    __shared__ short xb4[DD * DD];  // X4 bf16
    __shared__ float vb[2][DD];

    short* rh  = (short*)b0;  short* rl  = rh  + DD * DD;
    short* xh  = (short*)b1;  short* xl  = xh  + DD * DD;
    short* x2h = (short*)b2;  short* x2l = x2h + DD * DD;

    const int tid = threadIdx.x;
    const int bg  = blockIdx.x;
    const int b   = bg >> 3;        // batch
    const int g   = bg & 7;         // step-group: s in [16g, 16g+16)
    const int wv  = tid >> 6;       // wave 0..15 -> 16x16 tile (tr, tc)
    const int l   = tid & 63;
    const int tr  = wv >> 2, tc = wv & 3;
    const int q   = l >> 4;         // k-subgroup 0..3
    const int cl  = l & 15;
    const int mi  = tid >> 4, mh = tid & 15;

    const float alpha = alpha_p[b];
    const float beta  = beta_p[b];
    const float dt    = time_steps[0];   // uniform grid
    float kc[NN], rc[NN];
#pragma unroll
    for (int n = 0; n < NN; ++n) {
        kc[n] = k_coeffs[b * NN + n];
        rc[n] = r_coeffs[b * NN + n];
    }
    if (tid < DD) vb[0][tid] = z0[b * DD + tid];

    // ---- Phase A: Ksum fp32 (elem-XOR) -> b2; Rsum split-bf16 (SWZ) -> rh/rl ----
    {
        const int i  = tid >> 4;
        const int j0 = (tid & 15) * 4;
        const int e4 = i * DD + j0;
        float4 ks = make_float4(0.f, 0.f, 0.f, 0.f);
        float4 rs = make_float4(0.f, 0.f, 0.f, 0.f);
#pragma unroll
        for (int n = 0; n < NN; ++n) {
            float4 kb = *(const float4*)&K_bases[n * DD * DD + e4];
            float4 rb = *(const float4*)&R_bases[n * DD * DD + e4];
            ks.x = fmaf(kc[n], kb.x, ks.x); ks.y = fmaf(kc[n], kb.y, ks.y);
            ks.z = fmaf(kc[n], kb.z, ks.z); ks.w = fmaf(kc[n], kb.w, ks.w);
            rs.x = fmaf(rc[n], rb.x, rs.x); rs.y = fmaf(rc[n], rb.y, rs.y);
            rs.z = fmaf(rc[n], rb.z, rs.z); rs.w = fmaf(rc[n], rb.w, rs.w);
        }
        const int c = i & 31;
        b2[i * DD + ((j0 + 0) ^ c)] = ks.x;
        b2[i * DD + ((j0 + 1) ^ c)] = ks.y;
        b2[i * DD + ((j0 + 2) ^ c)] = ks.z;
        b2[i * DD + ((j0 + 3) ^ c)] = ks.w;
        float rv[4] = {rs.x, rs.y, rs.z, rs.w};
#pragma unroll
        for (int t = 0; t < 4; ++t) {
            unsigned short h  = f2bf(rv[t]);
            unsigned short lo = f2bf(rv[t] - bf2f(h));
            const int a = SWZ(i, j0 + t);
            rh[a] = (short)h; rl[a] = (short)lo;
        }
    }
    __syncthreads();

    // ---- MM1 (MFMA): RtR = R^T R; then X = dt*(alpha*(K-K^T) - beta*RtR) + eps*I ----
    f32x4 accR = {0.f, 0.f, 0.f, 0.f};
    {
        const int colA = 16 * tr + cl;   // A = R^T: row of A == column of R
        const int colB = 16 * tc + cl;
#pragma unroll
        for (int hK = 0; hK < 2; ++hK) {
            const int k0 = 32 * hK + 8 * q;
            bf16x8 aH = ldcol(rh, k0, colA), aL = ldcol(rl, k0, colA);
            bf16x8 bH = ldcol(rh, k0, colB), bL = ldcol(rl, k0, colB);
            accR = MFMA(aH, bH, accR);
            accR = MFMA(aH, bL, accR);
            accR = MFMA(aL, bH, accR);
        }
    }
    float xv[4];
#pragma unroll
    for (int r = 0; r < 4; ++r) {
        const int i = 16 * tr + 4 * q + r;
        const int j = 16 * tc + cl;
        const float kij = b2[i * DD + (j ^ (i & 31))];
        const float kji = b2[j * DD + (i ^ (j & 31))];
        float x = dt * (alpha * (kij - kji) - beta * accR[r]);
        if (i == j) x += EPS_;
        xv[r] = x;
    }
    __syncthreads();   // all rh/rl and Ksum reads complete
    // write X: fp32 -> b0 (overwrites rh/rl), split-bf16 -> xh/xl (b1)
#pragma unroll
    for (int r = 0; r < 4; ++r) {
        const int i = 16 * tr + 4 * q + r;
        const int j = 16 * tc + cl;
        b0[i * DD + j] = xv[r];
        unsigned short h  = f2bf(xv[r]);
        unsigned short lo = f2bf(xv[r] - bf2f(h));
        const int a = SWZ(i, j);
        xh[a] = (short)h; xl[a] = (short)lo;
    }
    __syncthreads();

    const int rowA = 16 * tr + cl;
    const int colB = 16 * tc + cl;

    // ---- MM2 (MFMA): X2 = X*X (split, 6 mfma) -> x2h/x2l (b2, Ksum dead) ----
    f32x4 acc2 = {0.f, 0.f, 0.f, 0.f};
#pragma unroll
    for (int hK = 0; hK < 2; ++hK) {
        const int k0 = 32 * hK + 8 * q;
        bf16x8 aH = ldrow(xh, rowA, k0), aL = ldrow(xl, rowA, k0);
        bf16x8 bH = ldcol(xh, k0, colB), bL = ldcol(xl, k0, colB);
        acc2 = MFMA(aH, bH, acc2);
        acc2 = MFMA(aH, bL, acc2);
        acc2 = MFMA(aL, bH, acc2);
    }
#pragma unroll
    for (int r = 0; r < 4; ++r) {
        const int i = 16 * tr + 4 * q + r;
        const int j = 16 * tc + cl;
        unsigned short h  = f2bf(acc2[r]);
        unsigned short lo = f2bf(acc2[r] - bf2f(h));
        const int a = SWZ(i, j);
        x2h[a] = (short)h; x2l[a] = (short)lo;
    }
    __syncthreads();

    // ---- L2 (MFMA): X3 = X2*X (split, 6), X4 = X2*X2 (plain, 2) -> xb4 ----
    f32x4 acc3 = {0.f, 0.f, 0.f, 0.f};
    f32x4 acc4 = {0.f, 0.f, 0.f, 0.f};
#pragma unroll
    for (int hK = 0; hK < 2; ++hK) {
        const int k0 = 32 * hK + 8 * q;
        bf16x8 aH  = ldrow(x2h, rowA, k0), aL = ldrow(x2l, rowA, k0);
        bf16x8 bxH = ldcol(xh,  k0, colB), bxL = ldcol(xl, k0, colB);
        bf16x8 b2H = ldcol(x2h, k0, colB);
        acc3 = MFMA(aH, bxH, acc3);
        acc3 = MFMA(aH, bxL, acc3);
        acc3 = MFMA(aL, bxH, acc3);
        acc4 = MFMA(aH, b2H, acc4);
    }
#pragma unroll
    for (int r = 0; r < 4; ++r) {
        const int i = 16 * tr + 4 * q + r;
        const int j = 16 * tc + cl;
        xb4[SWZ(i, j)] = (short)f2bf(acc4[r]);
    }
    __syncthreads();

    // ---- L3 (MFMA): X5 = X4*X (2), X6 = X4*X2 (2) ----
    f32x4 acc5 = {0.f, 0.f, 0.f, 0.f};
    f32x4 acc6 = {0.f, 0.f, 0.f, 0.f};
#pragma unroll
    for (int hK = 0; hK < 2; ++hK) {
        const int k0 = 32 * hK + 8 * q;
        bf16x8 a4  = ldrow(xb4, rowA, k0);
        bf16x8 bx  = ldcol(xh,  k0, colB);
        bf16x8 bx2 = ldcol(x2h, k0, colB);
        acc5 = MFMA(a4, bx,  acc5);
        acc6 = MFMA(a4, bx2, acc6);
    }
    __syncthreads();   // all xh/xl/x2h/xb4 reads done before overwrite

    // ---- Elementwise deg-6 combos: M -> b0, M32 -> b1, M16 -> b2 ----
#pragma unroll
    for (int r = 0; r < 4; ++r) {
        const int i = 16 * tr + 4 * q + r;
        const int j = 16 * tc + cl;
        const float d  = (i == j) ? 1.f : 0.f;
        const float x  = b0[i * DD + j];
        const float x2 = acc2[r], x3 = acc3[r], x4 = acc4[r];
        const float x5 = acc5[r], x6 = acc6[r];
        const float m1  = d + x + E1_2 * x2 + E1_3 * x3 + E1_4 * x4 + E1_5 * x5 + E1_6 * x6;
        const float m32 = d + E32_1 * x + E32_2 * x2 + E32_3 * x3 + E32_4 * x4 + E32_5 * x5 + E32_6 * x6;
        const float m16 = d + E16_1 * x + E16_2 * x2 + E16_3 * x3 + E16_4 * x4 + E16_5 * x5 + E16_6 * x6;
        b0[i * DD + j] = m1;
        b1[i * DD + j] = m32;
        b2[i * DD + j] = m16;
    }
    __syncthreads();

    // ---- base: v = M32^(g>>1) * M16^(g&1) * z0 = M^(16g) * z0 ----
    int pp = 0;
    const int n32 = g >> 1;
    for (int a = 0; a < n32; ++a) {
        float val = mv_step(b1, vb[pp], mi, mh);
        if (mh == 0) vb[pp ^ 1][mi] = val;
        __syncthreads();
        pp ^= 1;
    }
    if (g & 1) {
        float val = mv_step(b2, vb[pp], mi, mh);
        if (mh == 0) vb[pp ^ 1][mi] = val;
        __syncthreads();
        pp ^= 1;
    }

    // ---- chain: 16 steps with M; emit s = 16g + t ----
    for (int t = 0; t < GSTEP; ++t) {
        float val = mv_step(b0, vb[pp], mi, mh);
        if (mh == 0) {
            vb[pp ^ 1][mi] = val;
            const int s = g * GSTEP + t;
            const size_t oi = ((size_t)(b * SS + s)) * DD + mi;
            if (interleaved) ((float2*)out)[oi] = make_float2(val, 0.f);
            else             out[oi] = val;
        }
        __syncthreads();
        pp ^= 1;
    }
}

extern "C" void kernel_launch(void* const* d_in, const int* in_sizes, int n_in,
                              void* d_out, int out_size, void* d_ws, size_t ws_size,
                              hipStream_t stream) {
    const float* z0         = (const float*)d_in[0];
    const float* time_steps = (const float*)d_in[1];
    const float* k_coeffs   = (const float*)d_in[2];
    const float* r_coeffs   = (const float*)d_in[3];
    const float* alpha      = (const float*)d_in[4];
    const float* beta       = (const float*)d_in[5];
    const float* K_bases    = (const float*)d_in[6];
    const float* R_bases    = (const float*)d_in[7];
    float* out = (float*)d_out;

    const int n_z = BATCH * SS * DD;
    const int interleaved = (out_size >= 2 * n_z) ? 1 : 0;

    htg_kernel<<<dim3(BATCH * GROUPS), dim3(NTHREADS), 0, stream>>>(
        z0, time_steps, k_coeffs, r_coeffs, alpha, beta, K_bases, R_bases,
        out, interleaved);
}

// Round 7
// 17.482 us; speedup vs baseline: 2.3663x; 1.2899x over previous
//
#include <hip/hip_runtime.h>

#define BATCH 32
#define DD 64
#define NN 8
#define SS 128
#define EPS_ 1e-6f
#define NTHREADS 1024
#define NK 16          // Krylov depth: u_0..u_NK, deg-16 exp series

typedef __attribute__((ext_vector_type(8))) short bf16x8;
typedef __attribute__((ext_vector_type(4))) float f32x4;

__device__ __forceinline__ unsigned short f2bf(float f) {
    unsigned u = __float_as_uint(f);
    unsigned r = u + 0x7FFFu + ((u >> 16) & 1u);   // round-to-nearest-even
    return (unsigned short)(r >> 16);
}
__device__ __forceinline__ float bf2f(unsigned short h) {
    return __uint_as_float(((unsigned)h) << 16);
}
// swizzled element index in a [64][64] bf16 matrix: 8-elem k-blocks contiguous,
// block index XORed with (row&7) so column reads spread across banks
__device__ __forceinline__ int SWZ(int r, int c) {
    return r * 64 + (((c & ~7) ^ ((r & 7) << 3)) | (c & 7));
}
__device__ __forceinline__ bf16x8 ldcol(const short* m, int k0, int col) {
    bf16x8 v;
#pragma unroll
    for (int i = 0; i < 8; ++i) v[i] = m[SWZ(k0 + i, col)];
    return v;
}

#define MFMA(a, b, c) __builtin_amdgcn_mfma_f32_16x16x32_bf16((a), (b), (c), 0, 0, 0)

__launch_bounds__(NTHREADS)
__global__ void htg_kernel(const float* __restrict__ z0,
                           const float* __restrict__ time_steps,
                           const float* __restrict__ k_coeffs,
                           const float* __restrict__ r_coeffs,
                           const float* __restrict__ alpha_p,
                           const float* __restrict__ beta_p,
                           const float* __restrict__ K_bases,
                           const float* __restrict__ R_bases,
                           float* __restrict__ out,
                           int interleaved)
{
    __shared__ float bK[DD * DD];        // Ksum fp32, elem-XOR layout
    __shared__ short rh[DD * DD];        // Rsum bf16 high
    __shared__ short rl[DD * DD];        // Rsum bf16 low (residual)
    __shared__ float bX[DD * DD];        // X fp32
    __shared__ float us[NK + 1][DD];     // Krylov vectors u_k = X^k z0

    const int tid = threadIdx.x;
    const int b   = blockIdx.x;          // batch
    const int wv  = tid >> 6;            // wave 0..15 -> 16x16 tile (tr, tc)
    const int l   = tid & 63;
    const int tr  = wv >> 2, tc = wv & 3;
    const int q   = l >> 4;              // k-subgroup 0..3
    const int cl  = l & 15;
    const int mi  = tid >> 4, mh = tid & 15;   // matvec row / k-chunk

    const float alpha = alpha_p[b];
    const float beta  = beta_p[b];
    const float dt    = time_steps[0];   // uniform grid
    float kc[NN], rc[NN];
#pragma unroll
    for (int n = 0; n < NN; ++n) {
        kc[n] = k_coeffs[b * NN + n];
        rc[n] = r_coeffs[b * NN + n];
    }
    if (tid < DD) us[0][tid] = z0[b * DD + tid];

    // ---- Phase A: Ksum fp32 (elem-XOR) -> bK; Rsum split-bf16 (SWZ) -> rh/rl ----
    {
        const int i  = tid >> 4;
        const int j0 = (tid & 15) * 4;
        const int e4 = i * DD + j0;
        float4 ks = make_float4(0.f, 0.f, 0.f, 0.f);
        float4 rs = make_float4(0.f, 0.f, 0.f, 0.f);
#pragma unroll
        for (int n = 0; n < NN; ++n) {
            float4 kb = *(const float4*)&K_bases[n * DD * DD + e4];
            float4 rb = *(const float4*)&R_bases[n * DD * DD + e4];
            ks.x = fmaf(kc[n], kb.x, ks.x); ks.y = fmaf(kc[n], kb.y, ks.y);
            ks.z = fmaf(kc[n], kb.z, ks.z); ks.w = fmaf(kc[n], kb.w, ks.w);
            rs.x = fmaf(rc[n], rb.x, rs.x); rs.y = fmaf(rc[n], rb.y, rs.y);
            rs.z = fmaf(rc[n], rb.z, rs.z); rs.w = fmaf(rc[n], rb.w, rs.w);
        }
        const int c = i & 31;
        bK[i * DD + ((j0 + 0) ^ c)] = ks.x;
        bK[i * DD + ((j0 + 1) ^ c)] = ks.y;
        bK[i * DD + ((j0 + 2) ^ c)] = ks.z;
        bK[i * DD + ((j0 + 3) ^ c)] = ks.w;
        float rv[4] = {rs.x, rs.y, rs.z, rs.w};
#pragma unroll
        for (int t = 0; t < 4; ++t) {
            unsigned short h  = f2bf(rv[t]);
            unsigned short lo = f2bf(rv[t] - bf2f(h));
            const int a = SWZ(i, j0 + t);
            rh[a] = (short)h; rl[a] = (short)lo;
        }
    }
    __syncthreads();

    // ---- MM1 (MFMA): RtR = R^T R (split bf16); X = dt*(alpha*(K-K^T) - beta*RtR) + eps*I -> bX ----
    {
        f32x4 accR = {0.f, 0.f, 0.f, 0.f};
        const int colA = 16 * tr + cl;   // A = R^T: row of A == column of R
        const int colB = 16 * tc + cl;
#pragma unroll
        for (int hK = 0; hK < 2; ++hK) {
            const int k0 = 32 * hK + 8 * q;
            bf16x8 aH = ldcol(rh, k0, colA), aL = ldcol(rl, k0, colA);
            bf16x8 bH = ldcol(rh, k0, colB), bL = ldcol(rl, k0, colB);
            accR = MFMA(aH, bH, accR);
            accR = MFMA(aH, bL, accR);
            accR = MFMA(aL, bH, accR);
        }
#pragma unroll
        for (int r = 0; r < 4; ++r) {
            const int i = 16 * tr + 4 * q + r;
            const int j = 16 * tc + cl;
            const float kij = bK[i * DD + (j ^ (i & 31))];
            const float kji = bK[j * DD + (i ^ (j & 31))];
            float x = dt * (alpha * (kij - kji) - beta * accR[r]);
            if (i == j) x += EPS_;
            bX[i * DD + j] = x;      // fresh buffer: no WAR hazard
        }
    }
    __syncthreads();

    // ---- Krylov: u_k = X * u_{k-1}, k = 1..NK (X chunk held in registers) ----
    const float4 xr = *(const float4*)&bX[mi * DD + 4 * mh];
    for (int k = 1; k <= NK; ++k) {
        float4 v = *(const float4*)&us[k - 1][4 * mh];
        float p = fmaf(xr.x, v.x, fmaf(xr.y, v.y, fmaf(xr.z, v.z, xr.w * v.w)));
        p += __shfl_xor(p, 1, 16);
        p += __shfl_xor(p, 2, 16);
        p += __shfl_xor(p, 4, 16);
        p += __shfl_xor(p, 8, 16);
        if (mh == 0) us[k][mi] = p;
        __syncthreads();
    }

    // ---- Output: z_s[i] = sum_k (s+1)^k/k! * u_k[i], all 128 steps in parallel ----
    {
        const int i  = tid & 63;
        const int sb = tid >> 6;         // 0..15
        float uk[NK + 1];
#pragma unroll
        for (int k = 0; k <= NK; ++k) uk[k] = us[k][i];
#pragma unroll
        for (int r = 0; r < 8; ++r) {
            const int s = sb + 16 * r;
            const float t = (float)(s + 1);
            float f = 1.f;
            float acc = uk[0];
#pragma unroll
            for (int k = 1; k <= NK; ++k) {
                f *= t * (1.f / (float)k);       // f = t^k / k!
                acc = fmaf(f, uk[k], acc);
            }
            const size_t oi = ((size_t)(b * SS + s)) * DD + i;
            if (interleaved) ((float2*)out)[oi] = make_float2(acc, 0.f);
            else             out[oi] = acc;
        }
    }
}

extern "C" void kernel_launch(void* const* d_in, const int* in_sizes, int n_in,
                              void* d_out, int out_size, void* d_ws, size_t ws_size,
                              hipStream_t stream) {
    const float* z0         = (const float*)d_in[0];
    const float* time_steps = (const float*)d_in[1];
    const float* k_coeffs   = (const float*)d_in[2];
    const float* r_coeffs   = (const float*)d_in[3];
    const float* alpha      = (const float*)d_in[4];
    const float* beta       = (const float*)d_in[5];
    const float* K_bases    = (const float*)d_in[6];
    const float* R_bases    = (const float*)d_in[7];
    float* out = (float*)d_out;

    const int n_z = BATCH * SS * DD;
    const int interleaved = (out_size >= 2 * n_z) ? 1 : 0;

    htg_kernel<<<dim3(BATCH), dim3(NTHREADS), 0, stream>>>(
        z0, time_steps, k_coeffs, r_coeffs, alpha, beta, K_bases, R_bases,
        out, interleaved);
}